// Round 1
// baseline (173.682 us; speedup 1.0000x reference)
//
#include <hip/hip_runtime.h>

// EnhancedMemoryStack: B=32768, S=16, D=64. All fp32 I/O; bf16 MFMA internally.
//
// Outputs (flat, concat): z_read_r [B*64], z_read_i [B*64], mem_new [B*16*128],
//                         new_ptr [B*16], active_slots [1]
//
// One wave handles one batch per iteration (S=16 rows = MFMA M dim).
// LDS per WG: 6 weights bf16 swizzled (48KB) + 4 waves * 8KB scratch = 80KB -> 2 WG/CU.

typedef __bf16 bf16x8 __attribute__((ext_vector_type(8)));
typedef float  f32x4  __attribute__((ext_vector_type(4)));

#define B_TOT   32768
#define GRID_WG 1024
#define NWAVES  (GRID_WG * 4)   // 4096 waves -> 8 batches per wave

__device__ __forceinline__ unsigned short f2bf(float x) {
  __bf16 h = (__bf16)x;
  return __builtin_bit_cast(unsigned short, h);
}

__device__ __forceinline__ float sigm(float x) { return 1.0f / (1.0f + expf(-x)); }

__global__ void ems_zero(unsigned int* c) { if (threadIdx.x == 0) *c = 0u; }

__global__ void ems_fin(const unsigned int* __restrict__ c, float* __restrict__ out) {
  if (threadIdx.x == 0) out[0] = (float)(*c) * (1.0f / 32768.0f);
}

__global__ void __launch_bounds__(256, 2)
ems_main(const float* __restrict__ z_real, const float* __restrict__ z_imag,
         const float* __restrict__ mem,    const float* __restrict__ ptrv,
         const float* __restrict__ ctrl,
         const float* __restrict__ wqr, const float* __restrict__ wqi,
         const float* __restrict__ wkr, const float* __restrict__ wki,
         const float* __restrict__ wvr, const float* __restrict__ wvi,
         float* __restrict__ out_zr, float* __restrict__ out_zi,
         float* __restrict__ out_mem, float* __restrict__ out_ptr,
         unsigned int* __restrict__ ws_cnt)
{
  // [0 .. 24576): 6 weight mats, bf16, row-major 64x64, 16B-chunk XOR swizzle per row
  // [24576 + wv*4096): per-wave scratch: sq (2048 ushort) = q_hat then v_T,
  //                                      sk (2048 ushort) = k_hat then attn
  __shared__ __align__(16) unsigned short lds[40960];

  // ---- stage weights fp32 -> bf16 into LDS (once per WG) ----
  #pragma unroll
  for (int m = 0; m < 6; ++m) {
    const float* wp = (m==0)?wqr:(m==1)?wqi:(m==2)?wkr:(m==3)?wki:(m==4)?wvr:wvi;
    for (int idx = (int)threadIdx.x; idx < 4096; idx += 256) {
      int e = idx >> 6, d = idx & 63;
      // chunk (8 bf16 = 16B) index d>>3, XOR'd with row low bits
      lds[m*4096 + e*64 + (((d>>3) ^ (e&7)) << 3) + (d&7)] = f2bf(wp[idx]);
    }
  }
  __syncthreads();

  const int tid  = (int)threadIdx.x;
  const int lane = tid & 63;
  const int wv   = tid >> 6;
  const int c    = lane & 15;   // MFMA row of A / col of B / col of C
  const int g    = lane >> 4;   // k-chunk group (A/B), row group (C/D)

  unsigned short* sq = &lds[24576 + wv * 4096];
  unsigned short* sk = sq + 2048;

  const float4* mem4 = (const float4*)mem;
  const float4* zr4  = (const float4*)z_real;
  const float4* zi4  = (const float4*)z_imag;
  float4* omem4 = (float4*)out_mem;

  float4 cm[8], cz[8], nm[8], nz[8];

  auto loadB = [&](int bb, float4* m4, float4* z4) {
    #pragma unroll
    for (int t4 = 0; t4 < 4; ++t4) {
      int i4 = bb*512 + c*32 + t4*8 + g*2;   // float4 index: row c, cols t4*32+g*8
      m4[2*t4]   = mem4[i4];
      m4[2*t4+1] = mem4[i4+1];
    }
    int zb = bb*16 + g*2;
    z4[0] = zr4[zb];   z4[1] = zr4[zb+1];    // z_real[g*8..], cols 0..31 slice
    z4[2] = zr4[zb+8]; z4[3] = zr4[zb+9];    // z_real[32+g*8..]
    z4[4] = zi4[zb];   z4[5] = zi4[zb+1];    // z_imag[g*8..]
    z4[6] = zi4[zb+8]; z4[7] = zi4[zb+9];    // z_imag[32+g*8..]
  };

  unsigned int active_acc = 0u;
  int b = (int)blockIdx.x * 4 + wv;
  if (b < B_TOT) loadB(b, cm, cz);

  bf16x8 zfrag;
  #pragma unroll
  for (int j = 0; j < 8; ++j) zfrag[j] = (__bf16)0.0f;

  while (b < B_TOT) {
    int nb = b + NWAVES;

    // ---------- gates + pointer update ----------
    float pu = sigm(ctrl[b*3+0]);
    float po = sigm(ctrl[b*3+1]);
    float st = sigm(ctrl[b*3+2]);
    float tot = pu + po + st + 1e-6f;
    pu /= tot; po /= tot; st /= tot;

    float pm = ptrv[b*16 + ((c+15)&15)];  // roll +1 : ptr[s-1]
    float pp = ptrv[b*16 + ((c+ 1)&15)];  // roll -1 : ptr[s+1]
    float pc = ptrv[b*16 + c];
    float np = pu*pm + po*pp + st*pc;
    if (g == 0) out_ptr[b*16 + c] = np;
    unsigned long long ball = __ballot(np > 0.1f);
    active_acc += (unsigned int)__popcll(ball & 0xFFFFull);

    float wrow[4];  // new_ptr for this lane's D rows s = g*4+i
    #pragma unroll
    for (int i = 0; i < 4; ++i) wrow[i] = __shfl(np, g*4 + i, 64);

    // ---------- mem_new (fp32 exact, stored) + A fragments ----------
    float omp = 1.0f - pu;
    bf16x8 af[4], afn[2];   // af[t]: x_hat cols t*32+g*8..+7 of row c; afn = -mi halves
    #pragma unroll
    for (int t4 = 0; t4 < 4; ++t4) {
      float4 a0 = cm[2*t4], a1 = cm[2*t4+1];
      float4 z0 = cz[2*t4], z1 = cz[2*t4+1];
      float4 r0, r1;
      r0.x = a0.x*omp + pu*z0.x;  r0.y = a0.y*omp + pu*z0.y;
      r0.z = a0.z*omp + pu*z0.z;  r0.w = a0.w*omp + pu*z0.w;
      r1.x = a1.x*omp + pu*z1.x;  r1.y = a1.y*omp + pu*z1.y;
      r1.z = a1.z*omp + pu*z1.z;  r1.w = a1.w*omp + pu*z1.w;
      int i4 = b*512 + c*32 + t4*8 + g*2;
      omem4[i4]   = r0;
      omem4[i4+1] = r1;
      af[t4][0]=(__bf16)r0.x; af[t4][1]=(__bf16)r0.y; af[t4][2]=(__bf16)r0.z; af[t4][3]=(__bf16)r0.w;
      af[t4][4]=(__bf16)r1.x; af[t4][5]=(__bf16)r1.y; af[t4][6]=(__bf16)r1.z; af[t4][7]=(__bf16)r1.w;
      if (t4 >= 2) {
        afn[t4-2][0]=(__bf16)(-r0.x); afn[t4-2][1]=(__bf16)(-r0.y);
        afn[t4-2][2]=(__bf16)(-r0.z); afn[t4-2][3]=(__bf16)(-r0.w);
        afn[t4-2][4]=(__bf16)(-r1.x); afn[t4-2][5]=(__bf16)(-r1.y);
        afn[t4-2][6]=(__bf16)(-r1.z); afn[t4-2][7]=(__bf16)(-r1.w);
      }
    }

    // ---------- prefetch next batch's mem/z (hides HBM latency) ----------
    if (nb < B_TOT) loadB(nb, nm, nz);

    // complex projection: yr = mr*Wr^T - mi*Wi^T ; yi = mr*Wi^T + mi*Wr^T
    auto proj = [&](int matr, int mati, int n, f32x4& ar, f32x4& ai) {
      int e  = n*16 + c;       // weight row (output dim) = B col
      int eb = e*64;
      int e7 = e & 7;
      #pragma unroll
      for (int t = 0; t < 2; ++t) {
        int ch = ((t*4 + g) ^ e7) << 3;
        bf16x8 fr = *(const bf16x8*)&lds[matr*4096 + eb + ch];
        bf16x8 fi = *(const bf16x8*)&lds[mati*4096 + eb + ch];
        ar = __builtin_amdgcn_mfma_f32_16x16x32_bf16(af[t],   fr, ar, 0,0,0);
        ai = __builtin_amdgcn_mfma_f32_16x16x32_bf16(af[t],   fi, ai, 0,0,0);
        ar = __builtin_amdgcn_mfma_f32_16x16x32_bf16(afn[t],  fi, ar, 0,0,0);
        ai = __builtin_amdgcn_mfma_f32_16x16x32_bf16(af[t+2], fr, ai, 0,0,0);
      }
    };

    // ---------- q, k projections -> swizzled LDS (row-major [16][128] bf16) ----------
    #pragma unroll
    for (int n = 0; n < 4; ++n) {
      f32x4 ar = {0.f,0.f,0.f,0.f}, ai = {0.f,0.f,0.f,0.f};
      proj(0, 1, n, ar, ai);
      #pragma unroll
      for (int i = 0; i < 4; ++i) {
        int r = g*4 + i;
        sq[r*128 + (((n*2 + (c>>3)) ^ r) << 3) + (c&7)]     = f2bf(ar[i]); // col n*16+c
        sq[r*128 + (((8 + n*2 + (c>>3)) ^ r) << 3) + (c&7)] = f2bf(ai[i]); // col 64+n*16+c
      }
    }
    #pragma unroll
    for (int n = 0; n < 4; ++n) {
      f32x4 ar = {0.f,0.f,0.f,0.f}, ai = {0.f,0.f,0.f,0.f};
      proj(2, 3, n, ar, ai);
      #pragma unroll
      for (int i = 0; i < 4; ++i) {
        int r = g*4 + i;
        sk[r*128 + (((n*2 + (c>>3)) ^ r) << 3) + (c&7)]     = f2bf(ar[i]);
        sk[r*128 + (((8 + n*2 + (c>>3)) ^ r) << 3) + (c&7)] = f2bf(ai[i]);
      }
    }

    // ---------- scores = q_hat . k_hat^T * 1/8, softmax over cols ----------
    f32x4 sc = {0.f,0.f,0.f,0.f};
    #pragma unroll
    for (int t = 0; t < 4; ++t) {
      int ch = ((t*4 + g) ^ c) << 3;
      bf16x8 aq = *(const bf16x8*)&sq[c*128 + ch];   // A: q_hat row c
      bf16x8 bk = *(const bf16x8*)&sk[c*128 + ch];   // B: k_hat row c (= B col c)
      sc = __builtin_amdgcn_mfma_f32_16x16x32_bf16(aq, bk, sc, 0,0,0);
    }
    float a4[4];
    #pragma unroll
    for (int i = 0; i < 4; ++i) {
      float s0 = sc[i] * 0.125f;
      float mx = s0;
      mx = fmaxf(mx, __shfl_xor(mx, 1, 64));
      mx = fmaxf(mx, __shfl_xor(mx, 2, 64));
      mx = fmaxf(mx, __shfl_xor(mx, 4, 64));
      mx = fmaxf(mx, __shfl_xor(mx, 8, 64));
      float ex = expf(s0 - mx);
      float sm = ex;
      sm += __shfl_xor(sm, 1, 64);
      sm += __shfl_xor(sm, 2, 64);
      sm += __shfl_xor(sm, 4, 64);
      sm += __shfl_xor(sm, 8, 64);
      a4[i] = ex / sm;   // attn[row g*4+i][col c]
    }

    // ---------- v projection -> v^T [128][16] bf16 into sq (q_hat dead) ----------
    #pragma unroll
    for (int n = 0; n < 4; ++n) {
      f32x4 ar = {0.f,0.f,0.f,0.f}, ai = {0.f,0.f,0.f,0.f};
      proj(4, 5, n, ar, ai);
      uint2 prk, pik;
      prk.x = (unsigned)f2bf(ar[0]) | ((unsigned)f2bf(ar[1]) << 16);
      prk.y = (unsigned)f2bf(ar[2]) | ((unsigned)f2bf(ar[3]) << 16);
      pik.x = (unsigned)f2bf(ai[0]) | ((unsigned)f2bf(ai[1]) << 16);
      pik.y = (unsigned)f2bf(ai[2]) | ((unsigned)f2bf(ai[3]) << 16);
      *(uint2*)&sq[(n*16 + c)*16 + g*4]      = prk;   // rows (slots) g*4..g*4+3
      *(uint2*)&sq[(64 + n*16 + c)*16 + g*4] = pik;
    }

    // ---------- attn -> [16][16] bf16 into sk (k_hat dead) ----------
    #pragma unroll
    for (int i = 0; i < 4; ++i) sk[(g*4+i)*16 + c] = f2bf(a4[i]);

    // ---------- PV: att_out = attn(16x16, K-padded to 32) * v_hat(16x128) ----------
    bf16x8 pa = zfrag;
    if (g < 2) pa = *(const bf16x8*)&sk[c*16 + g*8];      // A: attn row c, k=g*8..
    f32x4 o[8];
    #pragma unroll
    for (int n2 = 0; n2 < 8; ++n2) {
      bf16x8 bv = zfrag;
      if (g < 2) bv = *(const bf16x8*)&sq[(n2*16 + c)*16 + g*8]; // B: v^T row e, k=g*8..
      f32x4 zz = {0.f,0.f,0.f,0.f};
      o[n2] = __builtin_amdgcn_mfma_f32_16x16x32_bf16(pa, bv, zz, 0,0,0);
    }

    // ---------- weighted read-out: sum_s att_out[s][e] * new_ptr[s] ----------
    #pragma unroll
    for (int n2 = 0; n2 < 8; ++n2) {
      float pr = o[n2][0]*wrow[0] + o[n2][1]*wrow[1] + o[n2][2]*wrow[2] + o[n2][3]*wrow[3];
      pr += __shfl_xor(pr, 16, 64);
      pr += __shfl_xor(pr, 32, 64);
      if (g == 0 && n2 < 4)  out_zr[b*64 + n2*16 + c] = pr;
      if (g == 1 && n2 >= 4) out_zi[b*64 + (n2-4)*16 + c] = pr;
    }

    // rotate prefetch buffers
    #pragma unroll
    for (int j = 0; j < 8; ++j) { cm[j] = nm[j]; cz[j] = nz[j]; }
    b = nb;
  }

  if (lane == 0) atomicAdd(ws_cnt, active_acc);
}

extern "C" void kernel_launch(void* const* d_in, const int* in_sizes, int n_in,
                              void* d_out, int out_size, void* d_ws, size_t ws_size,
                              hipStream_t stream) {
  const float* z_real = (const float*)d_in[0];
  const float* z_imag = (const float*)d_in[1];
  const float* memp   = (const float*)d_in[2];
  const float* ptrv   = (const float*)d_in[3];
  const float* ctrl   = (const float*)d_in[4];
  const float* wq_r   = (const float*)d_in[5];
  const float* wq_i   = (const float*)d_in[6];
  const float* wk_r   = (const float*)d_in[7];
  const float* wk_i   = (const float*)d_in[8];
  const float* wv_r   = (const float*)d_in[9];
  const float* wv_i   = (const float*)d_in[10];

  float* out     = (float*)d_out;
  float* out_zr  = out;                       // B*D      = 2097152
  float* out_zi  = out + 2097152;             // B*D
  float* out_mem = out + 4194304;             // B*S*2D   = 67108864
  float* out_ptr = out + 71303168;            // B*S      = 524288
  float* out_sc  = out + 71827456;            // scalar

  unsigned int* cnt = (unsigned int*)d_ws;

  ems_zero<<<1, 64, 0, stream>>>(cnt);
  ems_main<<<GRID_WG, 256, 0, stream>>>(z_real, z_imag, memp, ptrv, ctrl,
                                        wq_r, wq_i, wk_r, wk_i, wv_r, wv_i,
                                        out_zr, out_zi, out_mem, out_ptr, cnt);
  ems_fin<<<1, 64, 0, stream>>>(cnt, out_sc);
}